// Round 2
// baseline (958.950 us; speedup 1.0000x reference)
//
#include <hip/hip_runtime.h>
#include <hip/hip_bf16.h>
#include <cstdint>
#include <cstddef>

#define ATTN_OFF (2u*2048u*2048u)   // adjacency comes first in d_out

typedef __attribute__((ext_vector_type(8))) short bf16x8;
typedef __attribute__((ext_vector_type(4))) float f32x4;

// ---------------------------------------------------------------------------
// Low-rank projection: out = (in @ u) @ v, f64 math.
// in: [4096, 256] (InT), u: [256,64] f32, v: [64,256] f32.
// TRANS=true stores out transposed per-(b,h) slab: out[((b*8+h)*32+d)*2048 + m]
// ---------------------------------------------------------------------------
template <typename InT, typename OutT, bool TRANS>
__global__ __launch_bounds__(256) void lowrank_kernel(
    const InT* __restrict__ in, const float* __restrict__ u,
    const float* __restrict__ v, OutT* __restrict__ out) {
  __shared__ double mid[4][64];
  int tid = threadIdx.x;
  int rr = tid >> 6;          // 0..3 (row within block)
  int j  = tid & 63;          // 0..63
  int row = blockIdx.x * 4 + rr;

  const InT* inr = in + (size_t)row * 256;
  double acc = 0.0;
#pragma unroll 8
  for (int kk = 0; kk < 256; ++kk)
    acc = fma((double)inr[kk], (double)u[kk * 64 + j], acc);
  mid[rr][j] = acc;
  __syncthreads();

#pragma unroll
  for (int cc = 0; cc < 4; ++cc) {
    int col = j + 64 * cc;
    double o = 0.0;
#pragma unroll 8
    for (int r = 0; r < 64; ++r)
      o = fma(mid[rr][r], (double)v[r * 256 + col], o);
    if (TRANS) {
      int b = row >> 11, m = row & 2047, hh = col >> 5, d = col & 31;
      out[(((size_t)(b * 8 + hh)) * 32 + d) * 2048 + m] = (OutT)o;
    } else {
      out[(size_t)row * 256 + col] = (OutT)o;
    }
  }
}

// ---------------------------------------------------------------------------
// Exact per-row top-k (k=32) kth-value via LDS histogram + candidate ranking.
// ---------------------------------------------------------------------------
__device__ __forceinline__ float find_kth(const float (&s)[64], float mx,
                                          int c, int pr,
                                          unsigned* hrow, float* crow,
                                          unsigned* cn,
                                          volatile float* kslot) {
#pragma unroll
  for (int i = 0; i < 8; ++i) hrow[c * 8 + i] = 0u;
  if (c == 0) { *cn = 0u; *kslot = -1e30f; }

#pragma unroll
  for (int jj = 0; jj < 64; ++jj) {
    int bb = (int)((mx - s[jj]) * 16.0f);
    bb = bb > 255 ? 255 : bb;
    atomicAdd(&hrow[bb], 1u);
  }

  unsigned cnt8 = 0;
#pragma unroll
  for (int i = 0; i < 8; ++i) cnt8 += hrow[c * 8 + i];
  unsigned pre = cnt8;
#pragma unroll
  for (int off = 1; off < 32; off <<= 1) {
    unsigned t = __shfl_up(pre, (unsigned)off, 32);
    if (c >= off) pre += t;
  }
  unsigned excl = pre - cnt8;
  bool flag = (excl < 32u) && (pre >= 32u);
  unsigned long long bal = __ballot(flag);
  unsigned grp = (unsigned)(bal >> (pr * 32));
  int src = __ffs(grp) - 1 + pr * 32;
  int Bm = 255; unsigned cbm = 0;
  if (flag) {
    unsigned cum = excl;
#pragma unroll
    for (int i = 0; i < 8; ++i) {
      unsigned hv = hrow[c * 8 + i];
      if (cum < 32u && cum + hv >= 32u) { Bm = c * 8 + i; cbm = cum; }
      cum += hv;
    }
  }
  int B = __shfl(Bm, src, 64);
  unsigned cbefore = (unsigned)__shfl((int)cbm, src, 64);
  unsigned need = 32u - cbefore;

#pragma unroll
  for (int jj = 0; jj < 64; ++jj) {
    int bb = (int)((mx - s[jj]) * 16.0f);
    bb = bb > 255 ? 255 : bb;
    if (bb == B) {
      unsigned idx = atomicAdd(cn, 1u);
      if (idx < 128u) crow[idx] = s[jj];
    }
  }
  unsigned n0 = *cn;
  n0 = n0 > 128u ? 128u : n0;

  for (unsigned ci = (unsigned)c; ci < n0; ci += 32u) {
    float x = crow[ci];
    unsigned r = 0;
    for (unsigned jj = 0; jj < n0; ++jj) {
      float y = crow[jj];
      r += (y > x || (y == x && jj < ci)) ? 1u : 0u;
    }
    if (r == need - 1u) *kslot = x;
  }
  return *kslot;
}

__device__ __forceinline__ void softmax_write(float (&s)[64], float mx,
                                              float kth, int c,
                                              float* __restrict__ orow) {
  float z = 0.0f;
#pragma unroll
  for (int jj = 0; jj < 64; ++jj) {
    float p = (s[jj] >= kth) ? expf(s[jj] - mx) : 0.0f;
    s[jj] = p;
    z += p;
  }
#pragma unroll
  for (int off = 16; off >= 1; off >>= 1) z += __shfl_xor(z, (unsigned)off, 32);
  float rz = 1.0f / z;
#pragma unroll
  for (int jj = 0; jj < 64; ++jj)
    orow[(jj >> 2) * 128 + (jj & 3) * 32 + c] = s[jj] * rz;
}

// ---------------------------------------------------------------------------
// Fused scores (f64) + exact top-32 + softmax. One block = 16 rows of one
// (b,h) slab. Each thread: 2 rows x 64 m-columns (scores in registers).
// ---------------------------------------------------------------------------
__global__ __launch_bounds__(256, 2) void attn_kernel(
    const double* __restrict__ q, const double* __restrict__ kt,
    float* __restrict__ attn) {
  __shared__ __align__(16) double q_lds[16][32];
  __shared__ __align__(16) double k_tile[32][128];
  __shared__ unsigned hist[16][256];
  __shared__ float cand[16][128];
  __shared__ unsigned ccnt[16];
  __shared__ volatile float kth_s[16];

  int tid = threadIdx.x;
  int bx = blockIdx.x;
  int slab = bx >> 7;       // b*8 + h
  int rowtile = bx & 127;
  int b = slab >> 3, hh = slab & 7;
  int lane = tid & 63, w = tid >> 6;
  int c = lane & 31, pr = lane >> 5;
  int r0loc = w * 4 + pr * 2;   // rows r0loc, r0loc+1 of this block's 16

  {
    int rloc = tid >> 4, dp = tid & 15;
    int n = rowtile * 16 + rloc;
    double2 qv = *(const double2*)(q + ((size_t)(b * 2048 + n)) * 256 +
                                   hh * 32 + dp * 2);
    ((double2*)q_lds)[tid] = qv;
  }

  const double* kslab = kt + (size_t)slab * (32 * 2048);
  float s0[64], s1[64];
  double acc0[4] = {0, 0, 0, 0}, acc1[4] = {0, 0, 0, 0};
  float mx0 = -1e30f, mx1 = -1e30f;
  const double INV = 0.17677669529663688110021109052621;  // 1/sqrt(32)

#pragma unroll
  for (int t = 0; t < 16; ++t) {
    __syncthreads();
#pragma unroll
    for (int jj = 0; jj < 8; ++jj) {
      int p = tid + 256 * jj;
      double2 val = *(const double2*)(kslab + (size_t)(p >> 6) * 2048 +
                                      t * 128 + (p & 63) * 2);
      ((double2*)k_tile)[p] = val;
    }
    __syncthreads();
#pragma unroll
    for (int dq = 0; dq < 4; ++dq) {
      double qa[8], qb[8];
#pragma unroll
      for (int dd = 0; dd < 8; ++dd) {
        qa[dd] = q_lds[r0loc][dq * 8 + dd];
        qb[dd] = q_lds[r0loc + 1][dq * 8 + dd];
      }
#pragma unroll
      for (int mi = 0; mi < 4; ++mi) {
        int ml = c + 32 * mi;
#pragma unroll
        for (int dd = 0; dd < 8; ++dd) {
          double kv = k_tile[dq * 8 + dd][ml];
          acc0[mi] = fma(qa[dd], kv, acc0[mi]);
          acc1[mi] = fma(qb[dd], kv, acc1[mi]);
        }
      }
    }
#pragma unroll
    for (int mi = 0; mi < 4; ++mi) {
      float f0 = (float)(acc0[mi] * INV);
      float f1 = (float)(acc1[mi] * INV);
      s0[t * 4 + mi] = f0;
      s1[t * 4 + mi] = f1;
      mx0 = fmaxf(mx0, f0);
      mx1 = fmaxf(mx1, f1);
      acc0[mi] = 0.0;
      acc1[mi] = 0.0;
    }
  }

#pragma unroll
  for (int off = 16; off >= 1; off >>= 1) {
    mx0 = fmaxf(mx0, __shfl_xor(mx0, (unsigned)off, 32));
    mx1 = fmaxf(mx1, __shfl_xor(mx1, (unsigned)off, 32));
  }

  int rl0 = r0loc, rl1 = r0loc + 1;
  float kth0 = find_kth(s0, mx0, c, pr, &hist[rl0][0], &cand[rl0][0],
                        &ccnt[rl0], &kth_s[rl0]);
  float kth1 = find_kth(s1, mx1, c, pr, &hist[rl1][0], &cand[rl1][0],
                        &ccnt[rl1], &kth_s[rl1]);

  int n0g = rowtile * 16 + rl0;
  float* o0 = attn + ((size_t)slab * 2048 + n0g) * 2048;
  float* o1 = attn + ((size_t)slab * 2048 + n0g + 1) * 2048;
  softmax_write(s0, mx0, kth0, c, o0);
  softmax_write(s1, mx1, kth1, c, o1);
}

// ---------------------------------------------------------------------------
// PV via MFMA with bf16 hi/lo split (3-term, ~2^-18 relative accuracy).
// out[b,n,h*32+dh] = sum_m attn[b,h,n,m] * v[b,m,h*32+dh]
// Block: 32 rows of one slab, all 32 dh. 4 waves = (rowtile 0/1) x (ntile 0/1),
// each wave one 16x16 output tile, full K=2048 in 16 chunks of 128.
// LDS rows padded to 152 bf16 (304 B): 16B-aligned b128, 2-way banks (free).
// ---------------------------------------------------------------------------
#define PVLD 152

__global__ __launch_bounds__(256) void pv_kernel(
    const float* __restrict__ attn, const float* __restrict__ v,
    float* __restrict__ out) {
  __shared__ __align__(16) unsigned short ph[32][PVLD];
  __shared__ __align__(16) unsigned short pl[32][PVLD];
  __shared__ __align__(16) unsigned short vh[32][PVLD];
  __shared__ __align__(16) unsigned short vl[32][PVLD];

  int tid = threadIdx.x;
  int slab = blockIdx.x >> 6;
  int rt = blockIdx.x & 63;
  int b = slab >> 3, hh = slab & 7;
  int l = tid & 63, w = tid >> 6;
  int rowtile = w >> 1, nt = w & 1;

  const float* aslab =
      attn + (size_t)slab * 2048 * 2048 + (size_t)rt * 32 * 2048;
  const float* vbase = v + (size_t)b * 2048 * 256 + hh * 32;

  f32x4 acc = {0.f, 0.f, 0.f, 0.f};
  int fr = l & 15, fk = (l >> 4) * 8;
  int arow = rowtile * 16 + fr;
  int brow = nt * 16 + fr;

  for (int t = 0; t < 16; ++t) {
    __syncthreads();
    // stage P chunk [32 rows][128 m] -> bf16 hi/lo
#pragma unroll
    for (int jj = 0; jj < 16; ++jj) {
      int e = tid + 256 * jj;
      int r = e >> 7, mc = e & 127;
      float f = aslab[(size_t)r * 2048 + t * 128 + mc];
      __hip_bfloat16 hb = __float2bfloat16(f);
      float lof = f - __bfloat162float(hb);
      __hip_bfloat16 lb = __float2bfloat16(lof);
      ph[r][mc] = *(unsigned short*)&hb;
      pl[r][mc] = *(unsigned short*)&lb;
    }
    // stage V chunk transposed [32 dh][128 m] -> bf16 hi/lo
#pragma unroll
    for (int jj = 0; jj < 16; ++jj) {
      int e = tid + 256 * jj;
      int m = e >> 5, dh = e & 31;
      float f = vbase[(size_t)(t * 128 + m) * 256 + dh];
      __hip_bfloat16 hb = __float2bfloat16(f);
      float lof = f - __bfloat162float(hb);
      __hip_bfloat16 lb = __float2bfloat16(lof);
      vh[dh][m] = *(unsigned short*)&hb;
      vl[dh][m] = *(unsigned short*)&lb;
    }
    __syncthreads();
#pragma unroll
    for (int ks = 0; ks < 4; ++ks) {
      int m0 = ks * 32 + fk;
      bf16x8 pa = *(const bf16x8*)&ph[arow][m0];
      bf16x8 pb = *(const bf16x8*)&pl[arow][m0];
      bf16x8 va = *(const bf16x8*)&vh[brow][m0];
      bf16x8 vb = *(const bf16x8*)&vl[brow][m0];
      acc = __builtin_amdgcn_mfma_f32_16x16x32_bf16(pa, va, acc, 0, 0, 0);
      acc = __builtin_amdgcn_mfma_f32_16x16x32_bf16(pa, vb, acc, 0, 0, 0);
      acc = __builtin_amdgcn_mfma_f32_16x16x32_bf16(pb, va, acc, 0, 0, 0);
    }
  }

  // D layout: col = lane&15, row = (lane>>4)*4 + reg
  int orow0 = rt * 32 + rowtile * 16 + (l >> 4) * 4;
  int ocol = hh * 32 + nt * 16 + (l & 15);
#pragma unroll
  for (int i = 0; i < 4; ++i)
    out[((size_t)(b * 2048 + orow0 + i)) * 256 + ocol] = acc[i];
}

// ---------------------------------------------------------------------------
// adjacency = sigmoid(el @ el^T), zero diagonal.  fp32 GEMM-NT, 64x64 tiles.
// ---------------------------------------------------------------------------
__global__ __launch_bounds__(256) void adj_kernel(const float* __restrict__ el,
                                                  float* __restrict__ adj) {
  __shared__ float a_lds[64][33];
  __shared__ float b_lds[64][33];
  int tid = threadIdx.x;
  int b = blockIdx.z, rt = blockIdx.y, ct = blockIdx.x;
  const float* elb = el + (size_t)b * 2048 * 256;
  int tr = tid >> 4, tc = tid & 15;
  float acc[4][4] = {};

  for (int kt = 0; kt < 8; ++kt) {
    __syncthreads();
#pragma unroll
    for (int jj = 0; jj < 8; ++jj) {
      int e = tid + 256 * jj;
      int r = e >> 5, d = e & 31;
      a_lds[r][d] = elb[(size_t)(rt * 64 + r) * 256 + kt * 32 + d];
      b_lds[r][d] = elb[(size_t)(ct * 64 + r) * 256 + kt * 32 + d];
    }
    __syncthreads();
#pragma unroll
    for (int kk = 0; kk < 32; ++kk) {
      float va[4], vb[4];
#pragma unroll
      for (int i = 0; i < 4; ++i) {
        va[i] = a_lds[tr * 4 + i][kk];
        vb[i] = b_lds[tc * 4 + i][kk];
      }
#pragma unroll
      for (int i = 0; i < 4; ++i)
#pragma unroll
        for (int j2 = 0; j2 < 4; ++j2)
          acc[i][j2] = fmaf(va[i], vb[j2], acc[i][j2]);
    }
  }
#pragma unroll
  for (int i = 0; i < 4; ++i) {
    int rg = rt * 64 + tr * 4 + i;
#pragma unroll
    for (int j2 = 0; j2 < 4; ++j2) {
      int cg = ct * 64 + tc * 4 + j2;
      float sg = 1.0f / (1.0f + expf(-acc[i][j2]));
      if (rg == cg) sg = 0.0f;
      adj[((size_t)b * 2048 + rg) * 2048 + cg] = sg;
    }
  }
}

// ---------------------------------------------------------------------------
extern "C" void kernel_launch(void* const* d_in, const int* in_sizes, int n_in,
                              void* d_out, int out_size, void* d_ws,
                              size_t ws_size, hipStream_t stream) {
  const float* x    = (const float*)d_in[0];
  const float* ne_u = (const float*)d_in[1];
  const float* ne_v = (const float*)d_in[2];
  const float* wq_u = (const float*)d_in[3];
  const float* wq_v = (const float*)d_in[4];
  const float* wk_u = (const float*)d_in[5];
  const float* wk_v = (const float*)d_in[6];
  const float* wv_u = (const float*)d_in[7];
  const float* wv_v = (const float*)d_in[8];
  const float* wo_u = (const float*)d_in[9];
  const float* wo_v = (const float*)d_in[10];
  const float* es_u = (const float*)d_in[11];
  const float* es_v = (const float*)d_in[12];

  float* adj  = (float*)d_out;
  float* attn = adj + (size_t)ATTN_OFF;

  char* ws = (char*)d_ws;
  double* h   = (double*)(ws);                          //  8 MB
  double* qd  = (double*)(ws + ((size_t)8 << 20));      //  8 MB
  double* ktd = (double*)(ws + ((size_t)16 << 20));     //  8 MB
  float*  v   = (float*) (ws + ((size_t)24 << 20));     //  4 MB
  float*  out = (float*) (ws + ((size_t)28 << 20));     //  4 MB
  float*  h2  = (float*) (ws + ((size_t)32 << 20));     //  4 MB
  float*  el  = (float*) (ws + ((size_t)36 << 20));     //  4 MB

  lowrank_kernel<float,  double, false><<<1024, 256, 0, stream>>>(x,  ne_u, ne_v, h);
  lowrank_kernel<double, double, false><<<1024, 256, 0, stream>>>(h,  wq_u, wq_v, qd);
  lowrank_kernel<double, double, true ><<<1024, 256, 0, stream>>>(h,  wk_u, wk_v, ktd);
  lowrank_kernel<double, float,  false><<<1024, 256, 0, stream>>>(h,  wv_u, wv_v, v);

  attn_kernel<<<2048, 256, 0, stream>>>(qd, ktd, attn);
  pv_kernel<<<1024, 256, 0, stream>>>(attn, v, out);

  lowrank_kernel<float, float, false><<<1024, 256, 0, stream>>>(out, wo_u, wo_v, h2);
  lowrank_kernel<float, float, false><<<1024, 256, 0, stream>>>(h2,  es_u, es_v, el);

  adj_kernel<<<dim3(32, 32, 2), 256, 0, stream>>>(el, adj);
}

// Round 3
// 631.389 us; speedup vs baseline: 1.5188x; 1.5188x over previous
//
#include <hip/hip_runtime.h>
#include <hip/hip_bf16.h>
#include <cstdint>
#include <cstddef>

#define ATTN_OFF (2u*2048u*2048u)   // adjacency comes first in d_out
#define SLOTS 48                    // compact top-k slots per row (k=32 + tie margin)

// ---------------------------------------------------------------------------
// Low-rank projection: out = (in @ u) @ v, f64 math.
// in: [4096, 256] (InT), u: [256,64] f32, v: [64,256] f32.
// TRANS=true stores out transposed per-(b,h) slab: out[((b*8+h)*32+d)*2048 + m]
// ---------------------------------------------------------------------------
template <typename InT, typename OutT, bool TRANS>
__global__ __launch_bounds__(256) void lowrank_kernel(
    const InT* __restrict__ in, const float* __restrict__ u,
    const float* __restrict__ v, OutT* __restrict__ out) {
  __shared__ double mid[4][64];
  int tid = threadIdx.x;
  int rr = tid >> 6;          // 0..3 (row within block)
  int j  = tid & 63;          // 0..63
  int row = blockIdx.x * 4 + rr;

  const InT* inr = in + (size_t)row * 256;
  double acc = 0.0;
#pragma unroll 8
  for (int kk = 0; kk < 256; ++kk)
    acc = fma((double)inr[kk], (double)u[kk * 64 + j], acc);
  mid[rr][j] = acc;
  __syncthreads();

#pragma unroll
  for (int cc = 0; cc < 4; ++cc) {
    int col = j + 64 * cc;
    double o = 0.0;
#pragma unroll 8
    for (int r = 0; r < 64; ++r)
      o = fma(mid[rr][r], (double)v[r * 256 + col], o);
    if (TRANS) {
      int b = row >> 11, m = row & 2047, hh = col >> 5, d = col & 31;
      out[(((size_t)(b * 8 + hh)) * 32 + d) * 2048 + m] = (OutT)o;
    } else {
      out[(size_t)row * 256 + col] = (OutT)o;
    }
  }
}

// ---------------------------------------------------------------------------
// Exact per-row top-k (k=32) kth-value via LDS histogram + candidate ranking.
// All ops are within one 32-lane half-wave handling one row.
// ---------------------------------------------------------------------------
__device__ __forceinline__ float find_kth(const float (&s)[64], float mx,
                                          int c, int pr,
                                          unsigned* hrow, float* crow,
                                          unsigned* cn,
                                          volatile float* kslot) {
#pragma unroll
  for (int i = 0; i < 8; ++i) hrow[c * 8 + i] = 0u;
  if (c == 0) { *cn = 0u; *kslot = -1e30f; }

#pragma unroll
  for (int jj = 0; jj < 64; ++jj) {
    int bb = (int)((mx - s[jj]) * 16.0f);
    bb = bb > 255 ? 255 : bb;
    atomicAdd(&hrow[bb], 1u);
  }

  unsigned cnt8 = 0;
#pragma unroll
  for (int i = 0; i < 8; ++i) cnt8 += hrow[c * 8 + i];
  unsigned pre = cnt8;
#pragma unroll
  for (int off = 1; off < 32; off <<= 1) {
    unsigned t = __shfl_up(pre, (unsigned)off, 32);
    if (c >= off) pre += t;
  }
  unsigned excl = pre - cnt8;
  bool flag = (excl < 32u) && (pre >= 32u);
  unsigned long long bal = __ballot(flag);
  unsigned grp = (unsigned)(bal >> (pr * 32));
  int src = __ffs(grp) - 1 + pr * 32;
  int Bm = 255; unsigned cbm = 0;
  if (flag) {
    unsigned cum = excl;
#pragma unroll
    for (int i = 0; i < 8; ++i) {
      unsigned hv = hrow[c * 8 + i];
      if (cum < 32u && cum + hv >= 32u) { Bm = c * 8 + i; cbm = cum; }
      cum += hv;
    }
  }
  int B = __shfl(Bm, src, 64);
  unsigned cbefore = (unsigned)__shfl((int)cbm, src, 64);
  unsigned need = 32u - cbefore;

#pragma unroll
  for (int jj = 0; jj < 64; ++jj) {
    int bb = (int)((mx - s[jj]) * 16.0f);
    bb = bb > 255 ? 255 : bb;
    if (bb == B) {
      unsigned idx = atomicAdd(cn, 1u);
      if (idx < 128u) crow[idx] = s[jj];
    }
  }
  unsigned n0 = *cn;
  n0 = n0 > 128u ? 128u : n0;

  for (unsigned ci = (unsigned)c; ci < n0; ci += 32u) {
    float x = crow[ci];
    unsigned r = 0;
    for (unsigned jj = 0; jj < n0; ++jj) {
      float y = crow[jj];
      r += (y > x || (y == x && jj < ci)) ? 1u : 0u;
    }
    if (r == need - 1u) *kslot = x;
  }
  return *kslot;
}

// Dense softmax row write + compact (idx, val) sidecar for sparse PV.
__device__ __forceinline__ void softmax_write(float (&s)[64], float mx,
                                              float kth, int c,
                                              float* __restrict__ orow,
                                              float* __restrict__ cval,
                                              unsigned short* __restrict__ cidx,
                                              unsigned* scnt) {
  float z = 0.0f;
#pragma unroll
  for (int jj = 0; jj < 64; ++jj) {
    float p = (s[jj] >= kth) ? expf(s[jj] - mx) : 0.0f;
    s[jj] = p;
    z += p;
  }
#pragma unroll
  for (int off = 16; off >= 1; off >>= 1) z += __shfl_xor(z, (unsigned)off, 32);
  float rz = 1.0f / z;

  // zero compact slots (this row's 32 lanes), then fill via LDS counter.
  for (int i = c; i < SLOTS; i += 32) { cval[i] = 0.0f; cidx[i] = 0; }
  if (c == 0) *scnt = 0u;

#pragma unroll
  for (int jj = 0; jj < 64; ++jj) {
    int m = (jj >> 2) * 128 + (jj & 3) * 32 + c;
    float p = s[jj] * rz;
    orow[m] = p;
    if (s[jj] > 0.0f) {
      unsigned sl = atomicAdd(scnt, 1u);
      if (sl < (unsigned)SLOTS) { cval[sl] = p; cidx[sl] = (unsigned short)m; }
    }
  }
}

// ---------------------------------------------------------------------------
// Fused scores (f64) + exact top-32 + softmax. One block = 16 rows of one
// (b,h) slab. Each thread: 2 rows x 64 m-columns (scores in registers).
// Also emits the compact (idx,val) sidecar consumed by pv_sparse_kernel.
// ---------------------------------------------------------------------------
__global__ __launch_bounds__(256, 2) void attn_kernel(
    const double* __restrict__ q, const double* __restrict__ kt,
    float* __restrict__ attn, float* __restrict__ pval,
    unsigned short* __restrict__ pidx) {
  __shared__ __align__(16) double q_lds[16][32];
  __shared__ __align__(16) double k_tile[32][128];
  __shared__ unsigned hist[16][256];
  __shared__ float cand[16][128];
  __shared__ unsigned ccnt[16];
  __shared__ unsigned scnt[16];
  __shared__ volatile float kth_s[16];

  int tid = threadIdx.x;
  int bx = blockIdx.x;
  int slab = bx >> 7;       // b*8 + h
  int rowtile = bx & 127;
  int b = slab >> 3, hh = slab & 7;
  int lane = tid & 63, w = tid >> 6;
  int c = lane & 31, pr = lane >> 5;
  int r0loc = w * 4 + pr * 2;   // rows r0loc, r0loc+1 of this block's 16

  {
    int rloc = tid >> 4, dp = tid & 15;
    int n = rowtile * 16 + rloc;
    double2 qv = *(const double2*)(q + ((size_t)(b * 2048 + n)) * 256 +
                                   hh * 32 + dp * 2);
    ((double2*)q_lds)[tid] = qv;
  }

  const double* kslab = kt + (size_t)slab * (32 * 2048);
  float s0[64], s1[64];
  double acc0[4] = {0, 0, 0, 0}, acc1[4] = {0, 0, 0, 0};
  float mx0 = -1e30f, mx1 = -1e30f;
  const double INV = 0.17677669529663688110021109052621;  // 1/sqrt(32)

#pragma unroll
  for (int t = 0; t < 16; ++t) {
    __syncthreads();
#pragma unroll
    for (int jj = 0; jj < 8; ++jj) {
      int p = tid + 256 * jj;
      double2 val = *(const double2*)(kslab + (size_t)(p >> 6) * 2048 +
                                      t * 128 + (p & 63) * 2);
      ((double2*)k_tile)[p] = val;
    }
    __syncthreads();
#pragma unroll
    for (int dq = 0; dq < 4; ++dq) {
      double qa[8], qb[8];
#pragma unroll
      for (int dd = 0; dd < 8; ++dd) {
        qa[dd] = q_lds[r0loc][dq * 8 + dd];
        qb[dd] = q_lds[r0loc + 1][dq * 8 + dd];
      }
#pragma unroll
      for (int mi = 0; mi < 4; ++mi) {
        int ml = c + 32 * mi;
#pragma unroll
        for (int dd = 0; dd < 8; ++dd) {
          double kv = k_tile[dq * 8 + dd][ml];
          acc0[mi] = fma(qa[dd], kv, acc0[mi]);
          acc1[mi] = fma(qb[dd], kv, acc1[mi]);
        }
      }
    }
#pragma unroll
    for (int mi = 0; mi < 4; ++mi) {
      float f0 = (float)(acc0[mi] * INV);
      float f1 = (float)(acc1[mi] * INV);
      s0[t * 4 + mi] = f0;
      s1[t * 4 + mi] = f1;
      mx0 = fmaxf(mx0, f0);
      mx1 = fmaxf(mx1, f1);
      acc0[mi] = 0.0;
      acc1[mi] = 0.0;
    }
  }

#pragma unroll
  for (int off = 16; off >= 1; off >>= 1) {
    mx0 = fmaxf(mx0, __shfl_xor(mx0, (unsigned)off, 32));
    mx1 = fmaxf(mx1, __shfl_xor(mx1, (unsigned)off, 32));
  }

  int rl0 = r0loc, rl1 = r0loc + 1;
  float kth0 = find_kth(s0, mx0, c, pr, &hist[rl0][0], &cand[rl0][0],
                        &ccnt[rl0], &kth_s[rl0]);
  float kth1 = find_kth(s1, mx1, c, pr, &hist[rl1][0], &cand[rl1][0],
                        &ccnt[rl1], &kth_s[rl1]);

  int n0g = rowtile * 16 + rl0;
  size_t rowg = (size_t)slab * 2048 + n0g;
  float* o0 = attn + rowg * 2048;
  float* o1 = attn + (rowg + 1) * 2048;
  float* cv = pval + rowg * SLOTS;
  unsigned short* ci = pidx + rowg * SLOTS;
  softmax_write(s0, mx0, kth0, c, o0, cv, ci, &scnt[rl0]);
  softmax_write(s1, mx1, kth1, c, o1, cv + SLOTS, ci + SLOTS, &scnt[rl1]);
}

// ---------------------------------------------------------------------------
// Sparse PV: out[b,n,h*32+dh] = sum over kept m of p * v[b,m,h*32+dh].
// Block = 8 rows of one slab x 32 dh. Pairs staged in LDS; zero-padded slots
// contribute 0. V (4 MB) is L2-resident; each 32-lane group gathers one
// contiguous 128 B line of V per slot.
// ---------------------------------------------------------------------------
__global__ __launch_bounds__(256) void pv_sparse_kernel(
    const float* __restrict__ pval, const unsigned short* __restrict__ pidx,
    const float* __restrict__ v, float* __restrict__ out) {
  __shared__ float vals[8][SLOTS];
  __shared__ unsigned short idxs[8][SLOTS];
  int tid = threadIdx.x;
  int grp = blockIdx.x;          // 16 slabs * 256 rowgroups
  int slab = grp >> 8;
  int rg = grp & 255;
  int b = slab >> 3, hh = slab & 7;
  int r = tid >> 5, dh = tid & 31;

  for (int e = tid; e < 8 * SLOTS; e += 256) {
    int rr = e / SLOTS, ii = e % SLOTS;
    size_t base = ((size_t)slab * 2048 + rg * 8 + rr) * SLOTS + ii;
    vals[rr][ii] = pval[base];
    idxs[rr][ii] = pidx[base];
  }
  __syncthreads();

  const float* vb = v + (size_t)b * 2048 * 256 + hh * 32 + dh;
  float acc = 0.0f;
#pragma unroll 4
  for (int i = 0; i < SLOTS; ++i) {
    float p = vals[r][i];
    int m = idxs[r][i];
    acc = fmaf(p, vb[(size_t)m * 256], acc);
  }
  int n = rg * 8 + r;
  out[((size_t)(b * 2048 + n)) * 256 + hh * 32 + dh] = acc;
}

// ---------------------------------------------------------------------------
// adjacency = sigmoid(el @ el^T), zero diagonal.  fp32 GEMM-NT, 64x64 tiles.
// ---------------------------------------------------------------------------
__global__ __launch_bounds__(256) void adj_kernel(const float* __restrict__ el,
                                                  float* __restrict__ adj) {
  __shared__ float a_lds[64][33];
  __shared__ float b_lds[64][33];
  int tid = threadIdx.x;
  int b = blockIdx.z, rt = blockIdx.y, ct = blockIdx.x;
  const float* elb = el + (size_t)b * 2048 * 256;
  int tr = tid >> 4, tc = tid & 15;
  float acc[4][4] = {};

  for (int kt = 0; kt < 8; ++kt) {
    __syncthreads();
#pragma unroll
    for (int jj = 0; jj < 8; ++jj) {
      int e = tid + 256 * jj;
      int r = e >> 5, d = e & 31;
      a_lds[r][d] = elb[(size_t)(rt * 64 + r) * 256 + kt * 32 + d];
      b_lds[r][d] = elb[(size_t)(ct * 64 + r) * 256 + kt * 32 + d];
    }
    __syncthreads();
#pragma unroll
    for (int kk = 0; kk < 32; ++kk) {
      float va[4], vb[4];
#pragma unroll
      for (int i = 0; i < 4; ++i) {
        va[i] = a_lds[tr * 4 + i][kk];
        vb[i] = b_lds[tc * 4 + i][kk];
      }
#pragma unroll
      for (int i = 0; i < 4; ++i)
#pragma unroll
        for (int j2 = 0; j2 < 4; ++j2)
          acc[i][j2] = fmaf(va[i], vb[j2], acc[i][j2]);
    }
  }
#pragma unroll
  for (int i = 0; i < 4; ++i) {
    int rg = rt * 64 + tr * 4 + i;
#pragma unroll
    for (int j2 = 0; j2 < 4; ++j2) {
      int cg = ct * 64 + tc * 4 + j2;
      float sg = 1.0f / (1.0f + expf(-acc[i][j2]));
      if (rg == cg) sg = 0.0f;
      adj[((size_t)b * 2048 + rg) * 2048 + cg] = sg;
    }
  }
}

// ---------------------------------------------------------------------------
extern "C" void kernel_launch(void* const* d_in, const int* in_sizes, int n_in,
                              void* d_out, int out_size, void* d_ws,
                              size_t ws_size, hipStream_t stream) {
  const float* x    = (const float*)d_in[0];
  const float* ne_u = (const float*)d_in[1];
  const float* ne_v = (const float*)d_in[2];
  const float* wq_u = (const float*)d_in[3];
  const float* wq_v = (const float*)d_in[4];
  const float* wk_u = (const float*)d_in[5];
  const float* wk_v = (const float*)d_in[6];
  const float* wv_u = (const float*)d_in[7];
  const float* wv_v = (const float*)d_in[8];
  const float* wo_u = (const float*)d_in[9];
  const float* wo_v = (const float*)d_in[10];
  const float* es_u = (const float*)d_in[11];
  const float* es_v = (const float*)d_in[12];

  float* adj  = (float*)d_out;
  float* attn = adj + (size_t)ATTN_OFF;

  // Workspace map (40 MB total, with safe lifetime overlaps):
  //   h    0..8MB   (f64; dead once v is built -> pval overlays it)
  //   qd   8..16MB, ktd 16..24MB (f64; live through attn_kernel)
  //   v    24..28MB, out 28..32MB, h2 32..36MB
  //   el   36..40MB (written AFTER pv consumed pidx -> pidx overlays it)
  char* ws = (char*)d_ws;
  double* h    = (double*)(ws);
  double* qd   = (double*)(ws + ((size_t)8 << 20));
  double* ktd  = (double*)(ws + ((size_t)16 << 20));
  float*  v    = (float*) (ws + ((size_t)24 << 20));
  float*  out  = (float*) (ws + ((size_t)28 << 20));
  float*  h2   = (float*) (ws + ((size_t)32 << 20));
  float*  el   = (float*) (ws + ((size_t)36 << 20));
  float*  pval = (float*) (ws);                        // overlays dead h
  unsigned short* pidx = (unsigned short*)(ws + ((size_t)36 << 20)); // overlays el

  lowrank_kernel<float,  double, false><<<1024, 256, 0, stream>>>(x,  ne_u, ne_v, h);
  lowrank_kernel<double, double, false><<<1024, 256, 0, stream>>>(h,  wq_u, wq_v, qd);
  lowrank_kernel<double, double, true ><<<1024, 256, 0, stream>>>(h,  wk_u, wk_v, ktd);
  lowrank_kernel<double, float,  false><<<1024, 256, 0, stream>>>(h,  wv_u, wv_v, v);

  attn_kernel<<<2048, 256, 0, stream>>>(qd, ktd, attn, pval, pidx);
  pv_sparse_kernel<<<4096, 256, 0, stream>>>(pval, pidx, v, out);

  lowrank_kernel<float, float, false><<<1024, 256, 0, stream>>>(out, wo_u, wo_v, h2);
  lowrank_kernel<float, float, false><<<1024, 256, 0, stream>>>(h2,  es_u, es_v, el);

  adj_kernel<<<dim3(32, 32, 2), 256, 0, stream>>>(el, adj);
}

// Round 5
// 438.523 us; speedup vs baseline: 2.1868x; 1.4398x over previous
//
#include <hip/hip_runtime.h>
#include <hip/hip_bf16.h>
#include <cstdint>
#include <cstddef>

#define ATTN_OFF (2u*2048u*2048u)   // adjacency comes first in d_out
#define SLOTS 48                    // compact top-k slots per row
#define DELTA 1e-3f                 // boundary band half-width (>> bf16-split score err)
#define MAXB 16                     // max boundary elems per row
#define CCAP 96                     // candidate capacity for kth bucket

typedef __attribute__((ext_vector_type(8))) short bf16x8;
typedef __attribute__((ext_vector_type(4))) float f32x4;

__device__ __forceinline__ unsigned short bf16_hi(float f) {
  __hip_bfloat16 h = __float2bfloat16(f);
  return *(unsigned short*)&h;
}
__device__ __forceinline__ float bf16_val(unsigned short u) {
  __hip_bfloat16 h = *(__hip_bfloat16*)&u;
  return __bfloat162float(h);
}

// ---------------------------------------------------------------------------
// Low-rank projection: out = (in @ u) @ v, f64 math, ILP-4 accumulators.
// MODE 0: f64 out0 [row][256].
// MODE 1: f32 out0 [row][256].
// MODE 3: f64 out0 [row][256] (UNSCALED) + bf16 hi/lo split (out1/out2) of
//         (f32)(o*scale), head-sliced layout: [slab][m][d] with slab=b*8+h.
// ---------------------------------------------------------------------------
template <typename InT, int MODE>
__global__ __launch_bounds__(256) void lowrank_kernel(
    const InT* __restrict__ in, const float* __restrict__ u,
    const float* __restrict__ vw, void* __restrict__ out0,
    void* __restrict__ out1, void* __restrict__ out2, double scale) {
  __shared__ double mid[4][64];
  int tid = threadIdx.x;
  int rr = tid >> 6;          // 0..3 (row within block)
  int j  = tid & 63;          // 0..63
  int row = blockIdx.x * 4 + rr;

  const InT* inr = in + (size_t)row * 256;
  double a0 = 0, a1 = 0, a2 = 0, a3 = 0;
#pragma unroll 8
  for (int k4 = 0; k4 < 64; ++k4) {
    int kk = k4 * 4;
    a0 = fma((double)inr[kk + 0], (double)u[(kk + 0) * 64 + j], a0);
    a1 = fma((double)inr[kk + 1], (double)u[(kk + 1) * 64 + j], a1);
    a2 = fma((double)inr[kk + 2], (double)u[(kk + 2) * 64 + j], a2);
    a3 = fma((double)inr[kk + 3], (double)u[(kk + 3) * 64 + j], a3);
  }
  mid[rr][j] = (a0 + a1) + (a2 + a3);
  __syncthreads();

#pragma unroll
  for (int cc = 0; cc < 4; ++cc) {
    int col = j + 64 * cc;
    double o0 = 0, o1 = 0, o2 = 0, o3 = 0;
#pragma unroll 4
    for (int r4 = 0; r4 < 16; ++r4) {
      int r = r4 * 4;
      o0 = fma(mid[rr][r + 0], (double)vw[(r + 0) * 256 + col], o0);
      o1 = fma(mid[rr][r + 1], (double)vw[(r + 1) * 256 + col], o1);
      o2 = fma(mid[rr][r + 2], (double)vw[(r + 2) * 256 + col], o2);
      o3 = fma(mid[rr][r + 3], (double)vw[(r + 3) * 256 + col], o3);
    }
    double o = (o0 + o1) + (o2 + o3);
    if (MODE == 0) {
      ((double*)out0)[(size_t)row * 256 + col] = o;
    } else if (MODE == 1) {
      ((float*)out0)[(size_t)row * 256 + col] = (float)o;
    } else {
      ((double*)out0)[(size_t)row * 256 + col] = o;   // unscaled f64 sidecar
      int b = row >> 11, m = row & 2047, hh = col >> 5, d = col & 31;
      size_t addr = (((size_t)(b * 8 + hh)) * 2048 + m) * 32 + d;
      float f = (float)(o * scale);
      unsigned short hi = bf16_hi(f);
      float lof = f - bf16_val(hi);
      ((unsigned short*)out1)[addr] = hi;
      ((unsigned short*)out2)[addr] = bf16_hi(lof);
    }
  }
}

// ---------------------------------------------------------------------------
// Fused scores (MFMA bf16 hi/lo 3-term) + exact top-32 with f64 boundary
// refinement + softmax + dense write + compact sidecar.
// Block = 16 q-rows of one (b,h) slab, 512 threads (8 waves).
// Wave w owns m-slice [w*256, (w+1)*256): 16 MFMA tiles of 16 cols.
// C layout: col = tile*16 + (l&15), row = 4*(l>>4) + reg.
// ---------------------------------------------------------------------------
__global__ __launch_bounds__(512, 4) void attn_kernel(
    const unsigned short* __restrict__ qh, const unsigned short* __restrict__ ql,
    const unsigned short* __restrict__ kh, const unsigned short* __restrict__ kl,
    const double* __restrict__ qd, const double* __restrict__ kd,
    float* __restrict__ attn, float* __restrict__ pval,
    unsigned short* __restrict__ pidx) {
  __shared__ unsigned hist[16][256];
  __shared__ float cand[16][CCAP];
  __shared__ float rowmax_s[16][8];
  __shared__ float zpart_s[16][8];
  __shared__ float mx_s[16];
  __shared__ float kth_s[16];
  __shared__ float zinv_s[16];
  __shared__ int   kB_s[16];
  __shared__ unsigned kneed_s[16];
  __shared__ unsigned ccnt[16];
  __shared__ unsigned scnt[16];
  __shared__ unsigned chi_s[16];               // # definitely-in (s > kth+DELTA)
  __shared__ unsigned bcnt[16];                // boundary count
  __shared__ unsigned short bidx[16][MAXB];    // boundary col indices
  __shared__ unsigned short bkeep[16][MAXB];   // keep flags after f64 refine
  __shared__ double bs64[16][MAXB];            // refined f64 scores

  int tid = threadIdx.x;
  int bx  = blockIdx.x;
  int slab = bx >> 7;          // b*8+h
  int rowtile = bx & 127;
  int b = slab >> 3, hh = slab & 7;
  int w = tid >> 6;            // wave 0..7
  int l = tid & 63;
  int g = l >> 4;              // 0..3
  int li = l & 15;
  const double INV64 = 0.17677669529663688110021109052621;  // 1/sqrt(32)

  // ---- A fragments (q rows, shared by all waves) ----
  size_t qoff = (((size_t)slab * 2048 + rowtile * 16 + li) * 32) + g * 8;
  bf16x8 a_hi = *(const bf16x8*)(qh + qoff);
  bf16x8 a_lo = *(const bf16x8*)(ql + qoff);

  // ---- scores: 16 tiles x 3 MFMA ----
  float s[16][4];
  size_t kbase = ((size_t)slab * 2048 + w * 256 + li) * 32 + g * 8;
#pragma unroll
  for (int tt = 0; tt < 16; ++tt) {
    bf16x8 b_hi = *(const bf16x8*)(kh + kbase + (size_t)tt * 512);
    bf16x8 b_lo = *(const bf16x8*)(kl + kbase + (size_t)tt * 512);
    f32x4 acc = {0.f, 0.f, 0.f, 0.f};
    acc = __builtin_amdgcn_mfma_f32_16x16x32_bf16(a_hi, b_hi, acc, 0, 0, 0);
    acc = __builtin_amdgcn_mfma_f32_16x16x32_bf16(a_hi, b_lo, acc, 0, 0, 0);
    acc = __builtin_amdgcn_mfma_f32_16x16x32_bf16(a_lo, b_hi, acc, 0, 0, 0);
#pragma unroll
    for (int reg = 0; reg < 4; ++reg) s[tt][reg] = acc[reg];
  }

  // ---- phase 0b: zero LDS + sidecar slots, per-slice row max ----
  for (int i = tid; i < 16 * 256; i += 512) ((unsigned*)hist)[i] = 0u;
  if (tid < 16) {
    ccnt[tid] = 0u; scnt[tid] = 0u; chi_s[tid] = 0u; bcnt[tid] = 0u;
    kth_s[tid] = -1e30f; kB_s[tid] = -1;
  }
  size_t prow0 = ((size_t)slab * 2048 + rowtile * 16);
  for (int i = tid; i < 16 * SLOTS; i += 512) {
    pval[prow0 * SLOTS + i] = 0.0f;
    pidx[prow0 * SLOTS + i] = 0;
  }
  {
    float lmx[4];
#pragma unroll
    for (int reg = 0; reg < 4; ++reg) {
      float m = s[0][reg];
#pragma unroll
      for (int tt = 1; tt < 16; ++tt) m = fmaxf(m, s[tt][reg]);
      lmx[reg] = m;
    }
#pragma unroll
    for (int off = 1; off < 16; off <<= 1) {
#pragma unroll
      for (int reg = 0; reg < 4; ++reg)
        lmx[reg] = fmaxf(lmx[reg], __shfl_xor(lmx[reg], (unsigned)off, 16));
    }
    if (li == 0) {
#pragma unroll
      for (int reg = 0; reg < 4; ++reg) rowmax_s[4 * g + reg][w] = lmx[reg];
    }
  }
  __syncthreads();

  // ---- phase 1: block row max ----
  if (tid < 16) {
    float m = rowmax_s[tid][0];
#pragma unroll
    for (int i = 1; i < 8; ++i) m = fmaxf(m, rowmax_s[tid][i]);
    mx_s[tid] = m;
  }
  __syncthreads();

  // ---- phase 2: histogram fill ----
#pragma unroll
  for (int reg = 0; reg < 4; ++reg) {
    int rloc = 4 * g + reg;
    float mx = mx_s[rloc];
#pragma unroll
    for (int tt = 0; tt < 16; ++tt) {
      int bb = (int)((mx - s[tt][reg]) * 16.0f);
      bb = bb > 255 ? 255 : bb;
      atomicAdd(&hist[rloc][bb], 1u);
    }
  }
  __syncthreads();

  // ---- phase 3: scan -> kth bucket + rank-within-bucket needed ----
  if (w < 4) {
    int rloc = w * 4 + g;
    unsigned cnt16 = 0;
#pragma unroll
    for (int i = 0; i < 16; ++i) cnt16 += hist[rloc][li * 16 + i];
    unsigned pre = cnt16;
#pragma unroll
    for (int off = 1; off < 16; off <<= 1) {
      unsigned t = __shfl_up(pre, (unsigned)off, 16);
      if (li >= off) pre += t;
    }
    unsigned excl = pre - cnt16;
    bool flag = (excl < 32u) && (pre >= 32u);
    unsigned long long bal = __ballot(flag);
    unsigned seg = (unsigned)((bal >> (g * 16)) & 0xFFFFull);
    if (flag) {
      int src = __ffs(seg) - 1;
      if (li == src) {
        unsigned cum = excl;
        int B = 255; unsigned cb = 0;
#pragma unroll
        for (int i = 0; i < 16; ++i) {
          unsigned hv = hist[rloc][li * 16 + i];
          if (cum < 32u && cum + hv >= 32u) { B = li * 16 + i; cb = cum; }
          cum += hv;
        }
        kB_s[rloc] = B;
        kneed_s[rloc] = 32u - cb;
      }
    }
  }
  __syncthreads();

  // ---- phase 4: candidate collection ----
#pragma unroll
  for (int reg = 0; reg < 4; ++reg) {
    int rloc = 4 * g + reg;
    float mx = mx_s[rloc];
    int kB = kB_s[rloc];
#pragma unroll
    for (int tt = 0; tt < 16; ++tt) {
      int bb = (int)((mx - s[tt][reg]) * 16.0f);
      bb = bb > 255 ? 255 : bb;
      if (bb == kB) {
        unsigned slot = atomicAdd(&ccnt[rloc], 1u);
        if (slot < (unsigned)CCAP) cand[rloc][slot] = s[tt][reg];
      }
    }
  }
  __syncthreads();

  // ---- phase 5: exact fp32 kth among candidates ----
  if (w < 4) {
    int rloc = w * 4 + g;
    unsigned n0 = ccnt[rloc];
    n0 = n0 > (unsigned)CCAP ? (unsigned)CCAP : n0;
    unsigned need = kneed_s[rloc];
    if (need > n0) need = n0;
    for (unsigned ci = (unsigned)li; ci < n0; ci += 16u) {
      float x = cand[rloc][ci];
      unsigned r = 0;
      for (unsigned jj = 0; jj < n0; ++jj) {
        float y = cand[rloc][jj];
        r += (y > x || (y == x && jj < ci)) ? 1u : 0u;
      }
      if (r == need - 1u) kth_s[rloc] = x;
    }
  }
  __syncthreads();

  // ---- phase 6a: classification counts + boundary list ----
#pragma unroll
  for (int reg = 0; reg < 4; ++reg) {
    int rloc = 4 * g + reg;
    float kth = kth_s[rloc];
    unsigned cnt = 0;
#pragma unroll
    for (int tt = 0; tt < 16; ++tt) {
      float v = s[tt][reg];
      if (v > kth + DELTA) {
        ++cnt;
      } else if (!(v < kth - DELTA)) {
        unsigned slot = atomicAdd(&bcnt[rloc], 1u);
        if (slot < (unsigned)MAXB)
          bidx[rloc][slot] = (unsigned short)(w * 256 + tt * 16 + li);
      }
    }
#pragma unroll
    for (int off = 1; off < 16; off <<= 1)
      cnt += (unsigned)__shfl_xor((int)cnt, off, 16);
    if (li == 0) atomicAdd(&chi_s[rloc], cnt);
  }
  __syncthreads();

  // ---- phase 6b: f64 refinement of boundary elems (waves 0-3) ----
  if (w < 4) {
    int rloc = w * 4 + g;
    unsigned bn = bcnt[rloc];
    bn = bn > (unsigned)MAXB ? (unsigned)MAXB : bn;
    const double* qrow =
        qd + ((size_t)(b * 2048 + rowtile * 16 + rloc)) * 256 + hh * 32;
    for (unsigned ci = (unsigned)li; ci < bn; ci += 16u) {
      int m = bidx[rloc][ci];
      const double* krow = kd + ((size_t)(b * 2048 + m)) * 256 + hh * 32;
      double acc = 0.0;
#pragma unroll 8
      for (int d = 0; d < 32; ++d) acc = fma(qrow[d], krow[d], acc);
      bs64[rloc][ci] = acc * INV64;
    }
    // wave-lockstep: all slots written (bn<=16 -> one pass) before reads below
    unsigned need2 = 32u - chi_s[rloc];
    for (unsigned ci = (unsigned)li; ci < bn; ci += 16u) {
      double x = bs64[rloc][ci];
      unsigned r = 0;
      for (unsigned jj = 0; jj < bn; ++jj)
        r += (bs64[rloc][jj] > x) ? 1u : 0u;
      bkeep[rloc][ci] = (r < need2) ? 1 : 0;   // f64 ties: all kept (>= semantics)
    }
  }
  __syncthreads();

  // ---- phase 7: mask + exp + partial Z ----
  {
    float zs[4];
#pragma unroll
    for (int reg = 0; reg < 4; ++reg) {
      int rloc = 4 * g + reg;
      float mx = mx_s[rloc], kth = kth_s[rloc];
      unsigned bn = bcnt[rloc];
      bn = bn > (unsigned)MAXB ? (unsigned)MAXB : bn;
      float z = 0.0f;
#pragma unroll
      for (int tt = 0; tt < 16; ++tt) {
        float v = s[tt][reg];
        bool keep;
        if (v > kth + DELTA) {
          keep = true;
        } else if (v < kth - DELTA) {
          keep = false;
        } else {
          unsigned short col = (unsigned short)(w * 256 + tt * 16 + li);
          keep = (v >= kth);  // fallback (list overflow; ~impossible)
          for (unsigned jj = 0; jj < bn; ++jj) {
            if (bidx[rloc][jj] == col) { keep = bkeep[rloc][jj] != 0; break; }
          }
        }
        float p = keep ? __expf(v - mx) : 0.0f;
        s[tt][reg] = p;
        z += p;
      }
      zs[reg] = z;
    }
#pragma unroll
    for (int off = 1; off < 16; off <<= 1) {
#pragma unroll
      for (int reg = 0; reg < 4; ++reg)
        zs[reg] += __shfl_xor(zs[reg], (unsigned)off, 16);
    }
    if (li == 0) {
#pragma unroll
      for (int reg = 0; reg < 4; ++reg) zpart_s[4 * g + reg][w] = zs[reg];
    }
  }
  __syncthreads();

  // ---- phase 8: 1/Z ----
  if (tid < 16) {
    float z = 0.0f;
#pragma unroll
    for (int i = 0; i < 8; ++i) z += zpart_s[tid][i];
    zinv_s[tid] = 1.0f / z;
  }
  __syncthreads();

  // ---- phase 9: dense write + sidecar ----
#pragma unroll
  for (int reg = 0; reg < 4; ++reg) {
    int rloc = 4 * g + reg;
    float rz = zinv_s[rloc];
    float* pr = attn + (prow0 + rloc) * 2048 + w * 256 + li;
    float* pvr = pval + (prow0 + rloc) * SLOTS;
    unsigned short* pir = pidx + (prow0 + rloc) * SLOTS;
#pragma unroll
    for (int tt = 0; tt < 16; ++tt) {
      float p = s[tt][reg];
      float pn = p * rz;
      pr[tt * 16] = pn;
      if (p > 0.0f) {
        unsigned slot = atomicAdd(&scnt[rloc], 1u);
        if (slot < (unsigned)SLOTS) {
          pvr[slot] = pn;
          pir[slot] = (unsigned short)(w * 256 + tt * 16 + li);
        }
      }
    }
  }
}

// ---------------------------------------------------------------------------
// Sparse PV: out[b,n,h*32+dh] = sum over kept m of p * v[b,m,h*32+dh].
// ---------------------------------------------------------------------------
__global__ __launch_bounds__(256) void pv_sparse_kernel(
    const float* __restrict__ pval, const unsigned short* __restrict__ pidx,
    const float* __restrict__ v, float* __restrict__ out) {
  __shared__ float vals[8][SLOTS];
  __shared__ unsigned short idxs[8][SLOTS];
  int tid = threadIdx.x;
  int grp = blockIdx.x;          // 16 slabs * 256 rowgroups
  int slab = grp >> 8;
  int rg = grp & 255;
  int b = slab >> 3, hh = slab & 7;
  int r = tid >> 5, dh = tid & 31;

  for (int e = tid; e < 8 * SLOTS; e += 256) {
    int rr = e / SLOTS, ii = e % SLOTS;
    size_t base = ((size_t)slab * 2048 + rg * 8 + rr) * SLOTS + ii;
    vals[rr][ii] = pval[base];
    idxs[rr][ii] = pidx[base];
  }
  __syncthreads();

  const float* vb = v + (size_t)b * 2048 * 256 + hh * 32 + dh;
  float acc = 0.0f;
#pragma unroll 4
  for (int i = 0; i < SLOTS; ++i) {
    float p = vals[r][i];
    int m = idxs[r][i];
    acc = fmaf(p, vb[(size_t)m * 256], acc);
  }
  int n = rg * 8 + r;
  out[((size_t)(b * 2048 + n)) * 256 + hh * 32 + dh] = acc;
}

// ---------------------------------------------------------------------------
// adjacency = sigmoid(el @ el^T), zero diagonal.  fp32 GEMM-NT, 64x64 tiles.
// ---------------------------------------------------------------------------
__global__ __launch_bounds__(256) void adj_kernel(const float* __restrict__ el,
                                                  float* __restrict__ adj) {
  __shared__ float a_lds[64][33];
  __shared__ float b_lds[64][33];
  int tid = threadIdx.x;
  int b = blockIdx.z, rt = blockIdx.y, ct = blockIdx.x;
  const float* elb = el + (size_t)b * 2048 * 256;
  int tr = tid >> 4, tc = tid & 15;
  float acc[4][4] = {};

  for (int kt = 0; kt < 8; ++kt) {
    __syncthreads();
#pragma unroll
    for (int jj = 0; jj < 8; ++jj) {
      int e = tid + 256 * jj;
      int r = e >> 5, d = e & 31;
      a_lds[r][d] = elb[(size_t)(rt * 64 + r) * 256 + kt * 32 + d];
      b_lds[r][d] = elb[(size_t)(ct * 64 + r) * 256 + kt * 32 + d];
    }
    __syncthreads();
#pragma unroll
    for (int kk = 0; kk < 32; ++kk) {
      float va[4], vb[4];
#pragma unroll
      for (int i = 0; i < 4; ++i) {
        va[i] = a_lds[tr * 4 + i][kk];
        vb[i] = b_lds[tc * 4 + i][kk];
      }
#pragma unroll
      for (int i = 0; i < 4; ++i)
#pragma unroll
        for (int j2 = 0; j2 < 4; ++j2)
          acc[i][j2] = fmaf(va[i], vb[j2], acc[i][j2]);
    }
  }
#pragma unroll
  for (int i = 0; i < 4; ++i) {
    int rg = rt * 64 + tr * 4 + i;
#pragma unroll
    for (int j2 = 0; j2 < 4; ++j2) {
      int cg = ct * 64 + tc * 4 + j2;
      float sg = 1.0f / (1.0f + expf(-acc[i][j2]));
      if (rg == cg) sg = 0.0f;
      adj[((size_t)b * 2048 + rg) * 2048 + cg] = sg;
    }
  }
}

// ---------------------------------------------------------------------------
extern "C" void kernel_launch(void* const* d_in, const int* in_sizes, int n_in,
                              void* d_out, int out_size, void* d_ws,
                              size_t ws_size, hipStream_t stream) {
  const float* x    = (const float*)d_in[0];
  const float* ne_u = (const float*)d_in[1];
  const float* ne_v = (const float*)d_in[2];
  const float* wq_u = (const float*)d_in[3];
  const float* wq_v = (const float*)d_in[4];
  const float* wk_u = (const float*)d_in[5];
  const float* wk_v = (const float*)d_in[6];
  const float* wv_u = (const float*)d_in[7];
  const float* wv_v = (const float*)d_in[8];
  const float* wo_u = (const float*)d_in[9];
  const float* wo_v = (const float*)d_in[10];
  const float* es_u = (const float*)d_in[11];
  const float* es_v = (const float*)d_in[12];

  float* adj  = (float*)d_out;
  float* attn = adj + (size_t)ATTN_OFF;

  // Workspace map (39.2 MB peak, lifetime-overlapped):
  //   h    0..8MB   f64  (dead after v built)   <- pval overlays (6 MB)
  //   qd   8..16MB  f64  (live thru attn)       <- out 8..12, h2 12..16 after
  //   kd   16..24MB f64  (live thru attn)       <- el 16..20 after
  //   qh 24..26, ql 26..28, kh 28..30, kl 30..32 (bf16 split)
  //   v    32..36MB f32  (live thru pv)
  //   pidx 36..39.2MB u16
  char* ws = (char*)d_ws;
  double* h  = (double*)(ws);
  double* qd = (double*)(ws + ((size_t)8  << 20));
  double* kd = (double*)(ws + ((size_t)16 << 20));
  unsigned short* qh = (unsigned short*)(ws + ((size_t)24 << 20));
  unsigned short* ql = (unsigned short*)(ws + ((size_t)26 << 20));
  unsigned short* kh = (unsigned short*)(ws + ((size_t)28 << 20));
  unsigned short* kl = (unsigned short*)(ws + ((size_t)30 << 20));
  float* v    = (float*)(ws + ((size_t)32 << 20));
  unsigned short* pidx = (unsigned short*)(ws + ((size_t)36 << 20));
  float* pval = (float*)(ws);                          // overlays dead h
  float* out  = (float*)(ws + ((size_t)8  << 20));     // overlays qd (post-attn)
  float* h2   = (float*)(ws + ((size_t)12 << 20));     // overlays qd (post-attn)
  float* el   = (float*)(ws + ((size_t)16 << 20));     // overlays kd (post-attn)

  const double INV = 0.17677669529663688110021109052621;    // 1/sqrt(32)

  lowrank_kernel<float,  0><<<1024, 256, 0, stream>>>(x, ne_u, ne_v, h, nullptr, nullptr, 1.0);
  lowrank_kernel<double, 3><<<1024, 256, 0, stream>>>(h, wq_u, wq_v, qd, qh, ql, INV);
  lowrank_kernel<double, 3><<<1024, 256, 0, stream>>>(h, wk_u, wk_v, kd, kh, kl, 1.0);
  lowrank_kernel<double, 1><<<1024, 256, 0, stream>>>(h, wv_u, wv_v, v, nullptr, nullptr, 1.0);

  attn_kernel<<<2048, 512, 0, stream>>>(qh, ql, kh, kl, qd, kd, attn, pval, pidx);
  pv_sparse_kernel<<<4096, 256, 0, stream>>>(pval, pidx, v, out);

  lowrank_kernel<float, 1><<<1024, 256, 0, stream>>>(out, wo_u, wo_v, h2, nullptr, nullptr, 1.0);
  lowrank_kernel<float, 1><<<1024, 256, 0, stream>>>(h2, es_u, es_v, el, nullptr, nullptr, 1.0);

  adj_kernel<<<dim3(32, 32, 2), 256, 0, stream>>>(el, adj);
}

// Round 6
// 417.668 us; speedup vs baseline: 2.2960x; 1.0499x over previous
//
#include <hip/hip_runtime.h>
#include <hip/hip_bf16.h>
#include <cstdint>
#include <cstddef>

#define ATTN_OFF (2u*2048u*2048u)   // adjacency comes first in d_out
#define SLOTS 48                    // compact top-k slots per row
#define DELTA 1e-3f                 // boundary band half-width (>> bf16-split score err)
#define MAXB 16                     // max boundary elems per row
#define CCAP 96                     // candidate capacity for kth bucket

typedef __attribute__((ext_vector_type(8))) short bf16x8;
typedef __attribute__((ext_vector_type(4))) float f32x4;

__device__ __forceinline__ unsigned short bf16_hi(float f) {
  __hip_bfloat16 h = __float2bfloat16(f);
  return *(unsigned short*)&h;
}
__device__ __forceinline__ float bf16_val(unsigned short u) {
  __hip_bfloat16 h = *(__hip_bfloat16*)&u;
  return __bfloat162float(h);
}

// ---------------------------------------------------------------------------
// Fused node-embedding + Q/K/V low-rank chain, f64 math throughout.
// h = (x@ne_u)@ne_v lives only in LDS. Emits:
//   qd/kd: f64 [4096][256] (unscaled; refinement oracle)
//   qh/ql/kh/kl: bf16 hi/lo splits, head-sliced [slab][m][32] (q scaled by INV)
//   v: f32 [4096][256]
// Block = 4 rows, 256 threads (thread = (rr, j)).
// ---------------------------------------------------------------------------
__global__ __launch_bounds__(256) void fused_qkv_kernel(
    const float* __restrict__ x, const float* __restrict__ ne_u,
    const float* __restrict__ ne_v, const float* __restrict__ wq_u,
    const float* __restrict__ wq_v, const float* __restrict__ wk_u,
    const float* __restrict__ wk_v, const float* __restrict__ wv_u,
    const float* __restrict__ wv_v, double* __restrict__ qd,
    double* __restrict__ kd, unsigned short* __restrict__ qh,
    unsigned short* __restrict__ ql, unsigned short* __restrict__ kh,
    unsigned short* __restrict__ kl, float* __restrict__ v) {
  __shared__ double xm[4][64];
  __shared__ double hrow[4][256];
  __shared__ double mid2[4][64];

  int tid = threadIdx.x;
  int rr = tid >> 6;
  int j  = tid & 63;
  int row = blockIdx.x * 4 + rr;
  int b = row >> 11, m = row & 2047;
  const double INV = 0.17677669529663688110021109052621;  // 1/sqrt(32)

  // ---- ne stage 1: xm = x @ ne_u ----
  const float* xr = x + (size_t)row * 256;
  {
    double a0 = 0, a1 = 0, a2 = 0, a3 = 0;
#pragma unroll 8
    for (int k4 = 0; k4 < 64; ++k4) {
      int kk = k4 * 4;
      a0 = fma((double)xr[kk + 0], (double)ne_u[(kk + 0) * 64 + j], a0);
      a1 = fma((double)xr[kk + 1], (double)ne_u[(kk + 1) * 64 + j], a1);
      a2 = fma((double)xr[kk + 2], (double)ne_u[(kk + 2) * 64 + j], a2);
      a3 = fma((double)xr[kk + 3], (double)ne_u[(kk + 3) * 64 + j], a3);
    }
    xm[rr][j] = (a0 + a1) + (a2 + a3);
  }
  __syncthreads();

  // ---- ne stage 2: hrow = xm @ ne_v (LDS-resident h) ----
#pragma unroll
  for (int cc = 0; cc < 4; ++cc) {
    int col = j + 64 * cc;
    double o0 = 0, o1 = 0, o2 = 0, o3 = 0;
#pragma unroll 4
    for (int r4 = 0; r4 < 16; ++r4) {
      int r = r4 * 4;
      o0 = fma(xm[rr][r + 0], (double)ne_v[(r + 0) * 256 + col], o0);
      o1 = fma(xm[rr][r + 1], (double)ne_v[(r + 1) * 256 + col], o1);
      o2 = fma(xm[rr][r + 2], (double)ne_v[(r + 2) * 256 + col], o2);
      o3 = fma(xm[rr][r + 3], (double)ne_v[(r + 3) * 256 + col], o3);
    }
    hrow[rr][col] = (o0 + o1) + (o2 + o3);
  }
  __syncthreads();

  // ---- q / k / v projections off LDS h ----
  for (int p = 0; p < 3; ++p) {
    const float* pu = (p == 0) ? wq_u : (p == 1) ? wk_u : wv_u;
    const float* pw = (p == 0) ? wq_v : (p == 1) ? wk_v : wv_v;

    double a0 = 0, a1 = 0, a2 = 0, a3 = 0;
#pragma unroll 8
    for (int k4 = 0; k4 < 64; ++k4) {
      int kk = k4 * 4;
      a0 = fma(hrow[rr][kk + 0], (double)pu[(kk + 0) * 64 + j], a0);
      a1 = fma(hrow[rr][kk + 1], (double)pu[(kk + 1) * 64 + j], a1);
      a2 = fma(hrow[rr][kk + 2], (double)pu[(kk + 2) * 64 + j], a2);
      a3 = fma(hrow[rr][kk + 3], (double)pu[(kk + 3) * 64 + j], a3);
    }
    mid2[rr][j] = (a0 + a1) + (a2 + a3);
    __syncthreads();

#pragma unroll
    for (int cc = 0; cc < 4; ++cc) {
      int col = j + 64 * cc;
      double o0 = 0, o1 = 0, o2 = 0, o3 = 0;
#pragma unroll 4
      for (int r4 = 0; r4 < 16; ++r4) {
        int r = r4 * 4;
        o0 = fma(mid2[rr][r + 0], (double)pw[(r + 0) * 256 + col], o0);
        o1 = fma(mid2[rr][r + 1], (double)pw[(r + 1) * 256 + col], o1);
        o2 = fma(mid2[rr][r + 2], (double)pw[(r + 2) * 256 + col], o2);
        o3 = fma(mid2[rr][r + 3], (double)pw[(r + 3) * 256 + col], o3);
      }
      double o = (o0 + o1) + (o2 + o3);
      if (p == 2) {
        v[(size_t)row * 256 + col] = (float)o;
      } else {
        int hh = col >> 5, d = col & 31;
        size_t haddr = (((size_t)(b * 8 + hh)) * 2048 + m) * 32 + d;
        if (p == 0) {
          qd[(size_t)row * 256 + col] = o;
          float f = (float)(o * INV);
          unsigned short hi = bf16_hi(f);
          float lof = f - bf16_val(hi);
          qh[haddr] = hi;
          ql[haddr] = bf16_hi(lof);
        } else {
          kd[(size_t)row * 256 + col] = o;
          float f = (float)o;
          unsigned short hi = bf16_hi(f);
          float lof = f - bf16_val(hi);
          kh[haddr] = hi;
          kl[haddr] = bf16_hi(lof);
        }
      }
    }
    __syncthreads();   // protect mid2 before next projection
  }
}

// ---------------------------------------------------------------------------
// Low-rank projection (f64 math), remaining modes:
// MODE 1: f32 out0 [row][256]   (wo projection)
// MODE 4: bf16 hi/lo split out1/out2 [row][256]  (es projection -> adjacency)
// ---------------------------------------------------------------------------
template <typename InT, int MODE>
__global__ __launch_bounds__(256) void lowrank_kernel(
    const InT* __restrict__ in, const float* __restrict__ u,
    const float* __restrict__ vw, void* __restrict__ out0,
    void* __restrict__ out1, void* __restrict__ out2) {
  __shared__ double mid[4][64];
  int tid = threadIdx.x;
  int rr = tid >> 6;
  int j  = tid & 63;
  int row = blockIdx.x * 4 + rr;

  const InT* inr = in + (size_t)row * 256;
  double a0 = 0, a1 = 0, a2 = 0, a3 = 0;
#pragma unroll 8
  for (int k4 = 0; k4 < 64; ++k4) {
    int kk = k4 * 4;
    a0 = fma((double)inr[kk + 0], (double)u[(kk + 0) * 64 + j], a0);
    a1 = fma((double)inr[kk + 1], (double)u[(kk + 1) * 64 + j], a1);
    a2 = fma((double)inr[kk + 2], (double)u[(kk + 2) * 64 + j], a2);
    a3 = fma((double)inr[kk + 3], (double)u[(kk + 3) * 64 + j], a3);
  }
  mid[rr][j] = (a0 + a1) + (a2 + a3);
  __syncthreads();

#pragma unroll
  for (int cc = 0; cc < 4; ++cc) {
    int col = j + 64 * cc;
    double o0 = 0, o1 = 0, o2 = 0, o3 = 0;
#pragma unroll 4
    for (int r4 = 0; r4 < 16; ++r4) {
      int r = r4 * 4;
      o0 = fma(mid[rr][r + 0], (double)vw[(r + 0) * 256 + col], o0);
      o1 = fma(mid[rr][r + 1], (double)vw[(r + 1) * 256 + col], o1);
      o2 = fma(mid[rr][r + 2], (double)vw[(r + 2) * 256 + col], o2);
      o3 = fma(mid[rr][r + 3], (double)vw[(r + 3) * 256 + col], o3);
    }
    double o = (o0 + o1) + (o2 + o3);
    if constexpr (MODE == 1) {
      ((float*)out0)[(size_t)row * 256 + col] = (float)o;
    } else {
      float f = (float)o;
      unsigned short hi = bf16_hi(f);
      float lof = f - bf16_val(hi);
      ((unsigned short*)out1)[(size_t)row * 256 + col] = hi;
      ((unsigned short*)out2)[(size_t)row * 256 + col] = bf16_hi(lof);
    }
  }
}

// ---------------------------------------------------------------------------
// Fused scores (MFMA bf16 hi/lo 3-term) + exact top-32 with f64 boundary
// refinement + softmax + dense write + compact sidecar.  (verified R5)
// ---------------------------------------------------------------------------
__global__ __launch_bounds__(512, 4) void attn_kernel(
    const unsigned short* __restrict__ qh, const unsigned short* __restrict__ ql,
    const unsigned short* __restrict__ kh, const unsigned short* __restrict__ kl,
    const double* __restrict__ qd, const double* __restrict__ kd,
    float* __restrict__ attn, float* __restrict__ pval,
    unsigned short* __restrict__ pidx) {
  __shared__ unsigned hist[16][256];
  __shared__ float cand[16][CCAP];
  __shared__ float rowmax_s[16][8];
  __shared__ float zpart_s[16][8];
  __shared__ float mx_s[16];
  __shared__ float kth_s[16];
  __shared__ float zinv_s[16];
  __shared__ int   kB_s[16];
  __shared__ unsigned kneed_s[16];
  __shared__ unsigned ccnt[16];
  __shared__ unsigned scnt[16];
  __shared__ unsigned chi_s[16];
  __shared__ unsigned bcnt[16];
  __shared__ unsigned short bidx[16][MAXB];
  __shared__ unsigned short bkeep[16][MAXB];
  __shared__ double bs64[16][MAXB];

  int tid = threadIdx.x;
  int bx  = blockIdx.x;
  int slab = bx >> 7;
  int rowtile = bx & 127;
  int b = slab >> 3, hh = slab & 7;
  int w = tid >> 6;
  int l = tid & 63;
  int g = l >> 4;
  int li = l & 15;
  const double INV64 = 0.17677669529663688110021109052621;

  size_t qoff = (((size_t)slab * 2048 + rowtile * 16 + li) * 32) + g * 8;
  bf16x8 a_hi = *(const bf16x8*)(qh + qoff);
  bf16x8 a_lo = *(const bf16x8*)(ql + qoff);

  float s[16][4];
  size_t kbase = ((size_t)slab * 2048 + w * 256 + li) * 32 + g * 8;
#pragma unroll
  for (int tt = 0; tt < 16; ++tt) {
    bf16x8 b_hi = *(const bf16x8*)(kh + kbase + (size_t)tt * 512);
    bf16x8 b_lo = *(const bf16x8*)(kl + kbase + (size_t)tt * 512);
    f32x4 acc = {0.f, 0.f, 0.f, 0.f};
    acc = __builtin_amdgcn_mfma_f32_16x16x32_bf16(a_hi, b_hi, acc, 0, 0, 0);
    acc = __builtin_amdgcn_mfma_f32_16x16x32_bf16(a_hi, b_lo, acc, 0, 0, 0);
    acc = __builtin_amdgcn_mfma_f32_16x16x32_bf16(a_lo, b_hi, acc, 0, 0, 0);
#pragma unroll
    for (int reg = 0; reg < 4; ++reg) s[tt][reg] = acc[reg];
  }

  for (int i = tid; i < 16 * 256; i += 512) ((unsigned*)hist)[i] = 0u;
  if (tid < 16) {
    ccnt[tid] = 0u; scnt[tid] = 0u; chi_s[tid] = 0u; bcnt[tid] = 0u;
    kth_s[tid] = -1e30f; kB_s[tid] = -1;
  }
  size_t prow0 = ((size_t)slab * 2048 + rowtile * 16);
  for (int i = tid; i < 16 * SLOTS; i += 512) {
    pval[prow0 * SLOTS + i] = 0.0f;
    pidx[prow0 * SLOTS + i] = 0;
  }
  {
    float lmx[4];
#pragma unroll
    for (int reg = 0; reg < 4; ++reg) {
      float m = s[0][reg];
#pragma unroll
      for (int tt = 1; tt < 16; ++tt) m = fmaxf(m, s[tt][reg]);
      lmx[reg] = m;
    }
#pragma unroll
    for (int off = 1; off < 16; off <<= 1) {
#pragma unroll
      for (int reg = 0; reg < 4; ++reg)
        lmx[reg] = fmaxf(lmx[reg], __shfl_xor(lmx[reg], (unsigned)off, 16));
    }
    if (li == 0) {
#pragma unroll
      for (int reg = 0; reg < 4; ++reg) rowmax_s[4 * g + reg][w] = lmx[reg];
    }
  }
  __syncthreads();

  if (tid < 16) {
    float m = rowmax_s[tid][0];
#pragma unroll
    for (int i = 1; i < 8; ++i) m = fmaxf(m, rowmax_s[tid][i]);
    mx_s[tid] = m;
  }
  __syncthreads();

#pragma unroll
  for (int reg = 0; reg < 4; ++reg) {
    int rloc = 4 * g + reg;
    float mx = mx_s[rloc];
#pragma unroll
    for (int tt = 0; tt < 16; ++tt) {
      int bb = (int)((mx - s[tt][reg]) * 16.0f);
      bb = bb > 255 ? 255 : bb;
      atomicAdd(&hist[rloc][bb], 1u);
    }
  }
  __syncthreads();

  if (w < 4) {
    int rloc = w * 4 + g;
    unsigned cnt16 = 0;
#pragma unroll
    for (int i = 0; i < 16; ++i) cnt16 += hist[rloc][li * 16 + i];
    unsigned pre = cnt16;
#pragma unroll
    for (int off = 1; off < 16; off <<= 1) {
      unsigned t = __shfl_up(pre, (unsigned)off, 16);
      if (li >= off) pre += t;
    }
    unsigned excl = pre - cnt16;
    bool flag = (excl < 32u) && (pre >= 32u);
    unsigned long long bal = __ballot(flag);
    unsigned seg = (unsigned)((bal >> (g * 16)) & 0xFFFFull);
    if (flag) {
      int src = __ffs(seg) - 1;
      if (li == src) {
        unsigned cum = excl;
        int B = 255; unsigned cb = 0;
#pragma unroll
        for (int i = 0; i < 16; ++i) {
          unsigned hv = hist[rloc][li * 16 + i];
          if (cum < 32u && cum + hv >= 32u) { B = li * 16 + i; cb = cum; }
          cum += hv;
        }
        kB_s[rloc] = B;
        kneed_s[rloc] = 32u - cb;
      }
    }
  }
  __syncthreads();

#pragma unroll
  for (int reg = 0; reg < 4; ++reg) {
    int rloc = 4 * g + reg;
    float mx = mx_s[rloc];
    int kB = kB_s[rloc];
#pragma unroll
    for (int tt = 0; tt < 16; ++tt) {
      int bb = (int)((mx - s[tt][reg]) * 16.0f);
      bb = bb > 255 ? 255 : bb;
      if (bb == kB) {
        unsigned slot = atomicAdd(&ccnt[rloc], 1u);
        if (slot < (unsigned)CCAP) cand[rloc][slot] = s[tt][reg];
      }
    }
  }
  __syncthreads();

  if (w < 4) {
    int rloc = w * 4 + g;
    unsigned n0 = ccnt[rloc];
    n0 = n0 > (unsigned)CCAP ? (unsigned)CCAP : n0;
    unsigned need = kneed_s[rloc];
    if (need > n0) need = n0;
    for (unsigned ci = (unsigned)li; ci < n0; ci += 16u) {
      float x = cand[rloc][ci];
      unsigned r = 0;
      for (unsigned jj = 0; jj < n0; ++jj) {
        float y = cand[rloc][jj];
        r += (y > x || (y == x && jj < ci)) ? 1u : 0u;
      }
      if (r == need - 1u) kth_s[rloc] = x;
    }
  }
  __syncthreads();

#pragma unroll
  for (int reg = 0; reg < 4; ++reg) {
    int rloc = 4 * g + reg;
    float kth = kth_s[rloc];
    unsigned cnt = 0;
#pragma unroll
    for (int tt = 0; tt < 16; ++tt) {
      float v = s[tt][reg];
      if (v > kth + DELTA) {
        ++cnt;
      } else if (!(v < kth - DELTA)) {
        unsigned slot = atomicAdd(&bcnt[rloc], 1u);
        if (slot < (unsigned)MAXB)
          bidx[rloc][slot] = (unsigned short)(w * 256 + tt * 16 + li);
      }
    }
#pragma unroll
    for (int off = 1; off < 16; off <<= 1)
      cnt += (unsigned)__shfl_xor((int)cnt, off, 16);
    if (li == 0) atomicAdd(&chi_s[rloc], cnt);
  }
  __syncthreads();

  if (w < 4) {
    int rloc = w * 4 + g;
    unsigned bn = bcnt[rloc];
    bn = bn > (unsigned)MAXB ? (unsigned)MAXB : bn;
    const double* qrow =
        qd + ((size_t)(b * 2048 + rowtile * 16 + rloc)) * 256 + hh * 32;
    for (unsigned ci = (unsigned)li; ci < bn; ci += 16u) {
      int m = bidx[rloc][ci];
      const double* krow = kd + ((size_t)(b * 2048 + m)) * 256 + hh * 32;
      double acc = 0.0;
#pragma unroll 8
      for (int d = 0; d < 32; ++d) acc = fma(qrow[d], krow[d], acc);
      bs64[rloc][ci] = acc * INV64;
    }
    unsigned need2 = 32u - chi_s[rloc];
    for (unsigned ci = (unsigned)li; ci < bn; ci += 16u) {
      double x = bs64[rloc][ci];
      unsigned r = 0;
      for (unsigned jj = 0; jj < bn; ++jj)
        r += (bs64[rloc][jj] > x) ? 1u : 0u;
      bkeep[rloc][ci] = (r < need2) ? 1 : 0;
    }
  }
  __syncthreads();

  {
    float zs[4];
#pragma unroll
    for (int reg = 0; reg < 4; ++reg) {
      int rloc = 4 * g + reg;
      float mx = mx_s[rloc], kth = kth_s[rloc];
      unsigned bn = bcnt[rloc];
      bn = bn > (unsigned)MAXB ? (unsigned)MAXB : bn;
      float z = 0.0f;
#pragma unroll
      for (int tt = 0; tt < 16; ++tt) {
        float v = s[tt][reg];
        bool keep;
        if (v > kth + DELTA) {
          keep = true;
        } else if (v < kth - DELTA) {
          keep = false;
        } else {
          unsigned short col = (unsigned short)(w * 256 + tt * 16 + li);
          keep = (v >= kth);
          for (unsigned jj = 0; jj < bn; ++jj) {
            if (bidx[rloc][jj] == col) { keep = bkeep[rloc][jj] != 0; break; }
          }
        }
        float p = keep ? __expf(v - mx) : 0.0f;
        s[tt][reg] = p;
        z += p;
      }
      zs[reg] = z;
    }
#pragma unroll
    for (int off = 1; off < 16; off <<= 1) {
#pragma unroll
      for (int reg = 0; reg < 4; ++reg)
        zs[reg] += __shfl_xor(zs[reg], (unsigned)off, 16);
    }
    if (li == 0) {
#pragma unroll
      for (int reg = 0; reg < 4; ++reg) zpart_s[4 * g + reg][w] = zs[reg];
    }
  }
  __syncthreads();

  if (tid < 16) {
    float z = 0.0f;
#pragma unroll
    for (int i = 0; i < 8; ++i) z += zpart_s[tid][i];
    zinv_s[tid] = 1.0f / z;
  }
  __syncthreads();

#pragma unroll
  for (int reg = 0; reg < 4; ++reg) {
    int rloc = 4 * g + reg;
    float rz = zinv_s[rloc];
    float* pr = attn + (prow0 + rloc) * 2048 + w * 256 + li;
    float* pvr = pval + (prow0 + rloc) * SLOTS;
    unsigned short* pir = pidx + (prow0 + rloc) * SLOTS;
#pragma unroll
    for (int tt = 0; tt < 16; ++tt) {
      float p = s[tt][reg];
      float pn = p * rz;
      pr[tt * 16] = pn;
      if (p > 0.0f) {
        unsigned slot = atomicAdd(&scnt[rloc], 1u);
        if (slot < (unsigned)SLOTS) {
          pvr[slot] = pn;
          pir[slot] = (unsigned short)(w * 256 + tt * 16 + li);
        }
      }
    }
  }
}

// ---------------------------------------------------------------------------
// Sparse PV: out[b,n,h*32+dh] = sum over kept m of p * v[b,m,h*32+dh].
// ---------------------------------------------------------------------------
__global__ __launch_bounds__(256) void pv_sparse_kernel(
    const float* __restrict__ pval, const unsigned short* __restrict__ pidx,
    const float* __restrict__ v, float* __restrict__ out) {
  __shared__ float vals[8][SLOTS];
  __shared__ unsigned short idxs[8][SLOTS];
  int tid = threadIdx.x;
  int grp = blockIdx.x;
  int slab = grp >> 8;
  int rg = grp & 255;
  int b = slab >> 3, hh = slab & 7;
  int r = tid >> 5, dh = tid & 31;

  for (int e = tid; e < 8 * SLOTS; e += 256) {
    int rr = e / SLOTS, ii = e % SLOTS;
    size_t base = ((size_t)slab * 2048 + rg * 8 + rr) * SLOTS + ii;
    vals[rr][ii] = pval[base];
    idxs[rr][ii] = pidx[base];
  }
  __syncthreads();

  const float* vb = v + (size_t)b * 2048 * 256 + hh * 32 + dh;
  float acc = 0.0f;
#pragma unroll 4
  for (int i = 0; i < SLOTS; ++i) {
    float p = vals[r][i];
    int m = idxs[r][i];
    acc = fmaf(p, vb[(size_t)m * 256], acc);
  }
  int n = rg * 8 + r;
  out[((size_t)(b * 2048 + n)) * 256 + hh * 32 + dh] = acc;
}

// ---------------------------------------------------------------------------
// adjacency = sigmoid(el @ el^T), zero diagonal, via MFMA bf16 hi/lo 3-term.
// el pre-split into elh/ell [4096][256] by the es lowrank (no in-kernel
// conversion).  Block = 64x64 tile, 4 waves; wave w owns rows [w*16, w*16+16),
// 4 col-tiles of 16; fragments loaded directly from global (L2-resident).
// ---------------------------------------------------------------------------
__global__ __launch_bounds__(256) void adj_mfma_kernel(
    const unsigned short* __restrict__ elh, const unsigned short* __restrict__ ell,
    float* __restrict__ adj) {
  int tid = threadIdx.x;
  int l = tid & 63, w = tid >> 6;
  int li = l & 15, g = l >> 4;
  int b = blockIdx.z, rt = blockIdx.y, ct = blockIdx.x;

  int arow = rt * 64 + w * 16 + li;
  size_t abase = ((size_t)(b * 2048 + arow)) * 256 + g * 8;
  size_t bbase = ((size_t)(b * 2048 + ct * 64 + li)) * 256 + g * 8;

  f32x4 acc0 = {0.f, 0.f, 0.f, 0.f};
  f32x4 acc1 = {0.f, 0.f, 0.f, 0.f};
  f32x4 acc2 = {0.f, 0.f, 0.f, 0.f};
  f32x4 acc3 = {0.f, 0.f, 0.f, 0.f};

#pragma unroll
  for (int kc = 0; kc < 8; ++kc) {
    bf16x8 a_hi = *(const bf16x8*)(elh + abase + kc * 32);
    bf16x8 a_lo = *(const bf16x8*)(ell + abase + kc * 32);
#pragma unroll
    for (int t = 0; t < 4; ++t) {
      bf16x8 b_hi = *(const bf16x8*)(elh + bbase + (size_t)t * 16 * 256 + kc * 32);
      bf16x8 b_lo = *(const bf16x8*)(ell + bbase + (size_t)t * 16 * 256 + kc * 32);
      f32x4* pa = (t == 0) ? &acc0 : (t == 1) ? &acc1 : (t == 2) ? &acc2 : &acc3;
      *pa = __builtin_amdgcn_mfma_f32_16x16x32_bf16(a_hi, b_hi, *pa, 0, 0, 0);
      *pa = __builtin_amdgcn_mfma_f32_16x16x32_bf16(a_hi, b_lo, *pa, 0, 0, 0);
      *pa = __builtin_amdgcn_mfma_f32_16x16x32_bf16(a_lo, b_hi, *pa, 0, 0, 0);
    }
  }

  // C layout: col = l&15, row = (l>>4)*4 + reg
  int orow0 = rt * 64 + w * 16 + g * 4;
#pragma unroll
  for (int t = 0; t < 4; ++t) {
    f32x4 a = (t == 0) ? acc0 : (t == 1) ? acc1 : (t == 2) ? acc2 : acc3;
    int cg = ct * 64 + t * 16 + li;
#pragma unroll
    for (int i = 0; i < 4; ++i) {
      int rg = orow0 + i;
      float sg = 1.0f / (1.0f + __expf(-a[i]));
      if (rg == cg) sg = 0.0f;
      adj[((size_t)b * 2048 + rg) * 2048 + cg] = sg;
    }
  }
}

// ---------------------------------------------------------------------------
extern "C" void kernel_launch(void* const* d_in, const int* in_sizes, int n_in,
                              void* d_out, int out_size, void* d_ws,
                              size_t ws_size, hipStream_t stream) {
  const float* x    = (const float*)d_in[0];
  const float* ne_u = (const float*)d_in[1];
  const float* ne_v = (const float*)d_in[2];
  const float* wq_u = (const float*)d_in[3];
  const float* wq_v = (const float*)d_in[4];
  const float* wk_u = (const float*)d_in[5];
  const float* wk_v = (const float*)d_in[6];
  const float* wv_u = (const float*)d_in[7];
  const float* wv_v = (const float*)d_in[8];
  const float* wo_u = (const float*)d_in[9];
  const float* wo_v = (const float*)d_in[10];
  const float* es_u = (const float*)d_in[11];
  const float* es_v = (const float*)d_in[12];

  float* adj  = (float*)d_out;
  float* attn = adj + (size_t)ATTN_OFF;

  // Workspace map (38.2 MB peak, lifetime-overlapped):
  //   qd   0..8MB   f64 (live thru attn)  <- out 0..4, h2 4..8 after
  //   kd   8..16MB  f64 (live thru attn)  <- elh 8..10, ell 10..12 after
  //   qh 16..18, ql 18..20, kh 20..22, kl 22..24 (bf16 split)
  //   v    24..28MB f32 (live thru pv)
  //   pval 28..34.3MB f32, pidx 35..38.2MB u16
  char* ws = (char*)d_ws;
  double* qd = (double*)(ws);
  double* kd = (double*)(ws + ((size_t)8  << 20));
  unsigned short* qh = (unsigned short*)(ws + ((size_t)16 << 20));
  unsigned short* ql = (unsigned short*)(ws + ((size_t)18 << 20));
  unsigned short* kh = (unsigned short*)(ws + ((size_t)20 << 20));
  unsigned short* kl = (unsigned short*)(ws + ((size_t)22 << 20));
  float* v    = (float*)(ws + ((size_t)24 << 20));
  float* pval = (float*)(ws + ((size_t)28 << 20));
  unsigned short* pidx = (unsigned short*)(ws + ((size_t)35 << 20));
  float* out  = (float*)(ws);                          // overlays qd (post-attn)
  float* h2   = (float*)(ws + ((size_t)4  << 20));     // overlays qd (post-attn)
  unsigned short* elh = (unsigned short*)(ws + ((size_t)8  << 20)); // overlays kd
  unsigned short* ell = (unsigned short*)(ws + ((size_t)10 << 20)); // overlays kd

  fused_qkv_kernel<<<1024, 256, 0, stream>>>(
      x, ne_u, ne_v, wq_u, wq_v, wk_u, wk_v, wv_u, wv_v,
      qd, kd, qh, ql, kh, kl, v);

  attn_kernel<<<2048, 512, 0, stream>>>(qh, ql, kh, kl, qd, kd, attn, pval, pidx);
  pv_sparse_kernel<<<4096, 256, 0, stream>>>(pval, pidx, v, out);

  lowrank_kernel<float, 1><<<1024, 256, 0, stream>>>(out, wo_u, wo_v, h2, nullptr, nullptr);
  lowrank_kernel<float, 4><<<1024, 256, 0, stream>>>(h2, es_u, es_v, nullptr, elh, ell);

  adj_mfma_kernel<<<dim3(32, 32, 2), 256, 0, stream>>>(elh, ell, adj);
}